// Round 3
// baseline (89.682 us; speedup 1.0000x reference)
//
#include <hip/hip_runtime.h>
#include <math.h>

// Problem constants (fixed by setup_inputs)
#define NB 16
#define NA 5
#define NC 20
#define NH 64
#define NW 64
#define MAXGT 50
#define CELLS (NH * NW)           // 4096
#define CH (NA * (5 + NC))        // 125
#define TOTAL (NB * NA * NH * NW) // 327680
#define OBJECT_SCALE 5.0f

__device__ __forceinline__ float fast_sigmoid(float v) {
    return __builtin_amdgcn_rcpf(1.0f + __expf(-v));
}

// Fused kernel: 640 blocks x 256 threads, 2 cells/thread, 40 blocks/batch.
// First 50 threads of each block redundantly compute their batch's GT prep
// into LDS (trivial work, saves a kernel launch + ws round-trip).
__global__ __launch_bounds__(256) void yolo_loss_fused(
    const float* __restrict__ out, const float* __restrict__ tgt,
    const float* __restrict__ anc, float* __restrict__ d_out)
{
    __shared__ float4 s_box[MAXGT];    // {bx1,bx2,by1,by2}
    __shared__ float4 s_epi0[MAXGT];   // {tx,ty,tw,th}
    __shared__ float2 s_epi1[MAXGT];   // {tconf, cls}
    __shared__ float  s_thr[MAXGT];    // 0.375*gt_area (3e18 if invalid)
    __shared__ int    s_flat[MAXGT];   // scatter cell id (-1 if invalid)
    __shared__ float  ssum[4];

    int tid = threadIdx.x;
    int b = blockIdx.x / 40;           // 40 blocks per batch (block-uniform)

    // ---- inline GT prep (threads 0..49) ----
    if (tid < MAXGT) {
        const float* t = tgt + (size_t)(b * MAXGT + tid) * 5;
        float cls = t[0], xn = t[1], yn = t[2], wn = t[3], hn = t[4];
        bool valid = xn > 0.0f;
        float gx = xn * NW, gy = yn * NH, gw = wn * NW, gh = hn * NH;

        // best anchor (first max wins)
        int bn = 0; float best = -1.0f;
        for (int a = 0; a < NA; ++a) {
            float aw = anc[2 * a], ah = anc[2 * a + 1];
            float inter = fminf(aw, gw) * fminf(ah, gh);
            float uni = aw * ah + gw * gh - inter;
            float iou = uni > 0.0f ? inter / uni : 0.0f;
            if (iou > best) { best = iou; bn = a; }
        }
        float aw = anc[2 * bn], ah = anc[2 * bn + 1];
        int gi = (int)gx; gi = gi < 0 ? 0 : (gi > NW - 1 ? NW - 1 : gi);
        int gj = (int)gy; gj = gj < 0 ? 0 : (gj > NH - 1 ? NH - 1 : gj);
        int flat = ((b * NA + bn) * NH + gj) * NW + gi;

        // pred box at scatter cell -> tconf = IoU(pred, gt)
        int cell = gj * NW + gi;
        const float* base = out + ((size_t)b * CH + bn * 25) * CELLS + cell;
        float px = fast_sigmoid(base[0]) + (float)gi;
        float py = fast_sigmoid(base[CELLS]) + (float)gj;
        float pw = __expf(base[2 * CELLS]) * aw;
        float ph = __expf(base[3 * CELLS]) * ah;

        float bx1 = gx - gw * 0.5f, bx2 = gx + gw * 0.5f;
        float by1 = gy - gh * 0.5f, by2 = gy + gh * 0.5f;
        float ax1 = px - pw * 0.5f, ax2 = px + pw * 0.5f;
        float ay1 = py - ph * 0.5f, ay2 = py + ph * 0.5f;
        float iw = fmaxf(fminf(ax2, bx2) - fmaxf(ax1, bx1), 0.0f);
        float ih = fmaxf(fminf(ay2, by2) - fmaxf(ay1, by1), 0.0f);
        float inter = iw * ih;
        float uni = pw * ph + gw * gh - inter;
        float iou = uni > 0.0f ? inter / uni : 0.0f;

        if (valid) {
            s_box[tid] = make_float4(bx1, bx2, by1, by2);
            s_thr[tid] = 0.375f * (gw * gh);
            s_flat[tid] = flat;
        } else {
            s_box[tid] = make_float4(3e18f, -3e18f, 3e18f, -3e18f);
            s_thr[tid] = 3e18f;
            s_flat[tid] = -1;
        }
        s_epi0[tid] = make_float4(gx - (float)gi, gy - (float)gj,
                                  __logf(fmaxf(gw, 1e-12f) / aw),
                                  __logf(fmaxf(gh, 1e-12f) / ah));
        s_epi1[tid] = make_float2(iou, cls);
    }
    __syncthreads();

    // ---- per-cell loss, 2 adjacent cells per thread ----
    int q = blockIdx.x * 256 + tid;
    int id0 = 2 * q;                         // global cell ids id0, id0+1
    int r = id0 - b * (NA * CELLS);
    int a = r >> 12;                         // /CELLS (block-uniform)
    int cell = r & (CELLS - 1);
    int j = cell >> 6, i = cell & 63;        // i even; (i, i+1) same row

    const float* base = out + (((size_t)(b * CH + a * 25)) << 12) + cell;
    float2 xr = *(const float2*)(base);
    float2 yr = *(const float2*)(base + CELLS);
    float2 wr = *(const float2*)(base + 2 * CELLS);
    float2 hr = *(const float2*)(base + 3 * CELLS);
    float2 cr = *(const float2*)(base + 4 * CELLS);

    float aw = anc[2 * a], ah = anc[2 * a + 1];

    float sx0 = fast_sigmoid(xr.x), sx1 = fast_sigmoid(xr.y);
    float sy0 = fast_sigmoid(yr.x), sy1 = fast_sigmoid(yr.y);
    float pw0 = __expf(wr.x) * aw,  pw1 = __expf(wr.y) * aw;
    float ph0 = __expf(hr.x) * ah,  ph1 = __expf(hr.y) * ah;
    float px0 = sx0 + (float)i,     px1 = sx1 + (float)(i + 1);
    float py0 = sy0 + (float)j,     py1 = sy1 + (float)j;

    float ax1_0 = px0 - pw0 * 0.5f, ax2_0 = px0 + pw0 * 0.5f;
    float ay1_0 = py0 - ph0 * 0.5f, ay2_0 = py0 + ph0 * 0.5f;
    float ax1_1 = px1 - pw1 * 0.5f, ax2_1 = px1 + pw1 * 0.5f;
    float ay1_1 = py1 - ph1 * 0.5f, ay2_1 = py1 + ph1 * 0.5f;
    float pthr0 = 0.375f * (pw0 * ph0);
    float pthr1 = 0.375f * (pw1 * ph1);

    float sil0 = -1.0f, sil1 = -1.0f;
    int m0 = -1, m1 = -1;

    #pragma unroll 10
    for (int g = 0; g < MAXGT; ++g) {
        float4 B = s_box[g];
        float tg = s_thr[g];
        int fg = s_flat[g];

        float iw0 = fminf(ax2_0, B.y) - fmaxf(ax1_0, B.x);
        float ih0 = fminf(ay2_0, B.w) - fmaxf(ay1_0, B.z);
        float in0 = fmaxf(iw0, 0.0f) * fmaxf(ih0, 0.0f);
        sil0 = fmaxf(sil0, in0 - (pthr0 + tg));

        float iw1 = fminf(ax2_1, B.y) - fmaxf(ax1_1, B.x);
        float ih1 = fminf(ay2_1, B.w) - fmaxf(ay1_1, B.z);
        float in1 = fmaxf(iw1, 0.0f) * fmaxf(ih1, 0.0f);
        sil1 = fmaxf(sil1, in1 - (pthr1 + tg));

        m0 = (fg == id0)     ? g : m0;   // last-wins scatter semantics
        m1 = (fg == id0 + 1) ? g : m1;
    }

    float sc0 = fast_sigmoid(cr.x), sc1 = fast_sigmoid(cr.y);
    float loss = 0.0f;

    // --- cell 0 epilogue ---
    {
        float tx = 0.5f, ty = 0.5f, tw = 0.0f, th = 0.0f, tc = 0.0f;
        float cs = (sil0 > 0.0f) ? 0.0f : 1.0f;
        if (m0 >= 0) {
            float4 e0 = s_epi0[m0]; float2 e1 = s_epi1[m0];
            tx = e0.x; ty = e0.y; tw = e0.z; th = e0.w;
            tc = e1.x; cs = OBJECT_SCALE;
            int cls = (int)e1.y;
            const float* cl = base + 5 * CELLS;
            float mx = -1e30f;
            #pragma unroll
            for (int c = 0; c < NC; ++c) mx = fmaxf(mx, cl[c * CELLS]);
            float se = 0.0f, lt = 0.0f;
            #pragma unroll
            for (int c = 0; c < NC; ++c) {
                float v = cl[c * CELLS];
                se += __expf(v - mx);
                if (c == cls) lt = v;
            }
            loss += mx + __logf(se) - lt;
        }
        float dx = sx0 - tx, dy = sy0 - ty, dw = wr.x - tw, dh = hr.x - th, dc = sc0 - tc;
        loss += 0.5f * (dx * dx + dy * dy + dw * dw + dh * dh) + 0.5f * cs * dc * dc;
    }
    // --- cell 1 epilogue ---
    {
        float tx = 0.5f, ty = 0.5f, tw = 0.0f, th = 0.0f, tc = 0.0f;
        float cs = (sil1 > 0.0f) ? 0.0f : 1.0f;
        if (m1 >= 0) {
            float4 e0 = s_epi0[m1]; float2 e1 = s_epi1[m1];
            tx = e0.x; ty = e0.y; tw = e0.z; th = e0.w;
            tc = e1.x; cs = OBJECT_SCALE;
            int cls = (int)e1.y;
            const float* cl = base + 1 + 5 * CELLS;
            float mx = -1e30f;
            #pragma unroll
            for (int c = 0; c < NC; ++c) mx = fmaxf(mx, cl[c * CELLS]);
            float se = 0.0f, lt = 0.0f;
            #pragma unroll
            for (int c = 0; c < NC; ++c) {
                float v = cl[c * CELLS];
                se += __expf(v - mx);
                if (c == cls) lt = v;
            }
            loss += mx + __logf(se) - lt;
        }
        float dx = sx1 - tx, dy = sy1 - ty, dw = wr.y - tw, dh = hr.y - th, dc = sc1 - tc;
        loss += 0.5f * (dx * dx + dy * dy + dw * dw + dh * dh) + 0.5f * cs * dc * dc;
    }

    // wave-64 shuffle reduce -> cross-wave LDS -> one atomic per block
    float v = loss;
    #pragma unroll
    for (int off = 32; off > 0; off >>= 1) v += __shfl_down(v, off, 64);
    int lane = tid & 63, wv = tid >> 6;
    if (lane == 0) ssum[wv] = v;
    __syncthreads();
    if (tid == 0)
        atomicAdd(d_out, ssum[0] + ssum[1] + ssum[2] + ssum[3]);
}

extern "C" void kernel_launch(void* const* d_in, const int* in_sizes, int n_in,
                              void* d_out, int out_size, void* d_ws, size_t ws_size,
                              hipStream_t stream) {
    const float* out = (const float*)d_in[0];
    const float* tgt = (const float*)d_in[1];
    const float* anc = (const float*)d_in[2];
    float* o = (float*)d_out;

    hipMemsetAsync(o, 0, sizeof(float), stream);   // graph memset node
    yolo_loss_fused<<<(TOTAL / 2) / 256, 256, 0, stream>>>(out, tgt, anc, o);
}